// Round 1
// 1598.094 us; speedup vs baseline: 1.2279x; 1.2279x over previous
//
#include <hip/hip_runtime.h>
#include <math.h>
#include <stdint.h>

// ---------------- problem constants ----------------
#define T_STEPS 100
#define BATCH   128
#define EMB     64
#define RDIM    32
#define SDIM    32
#define INDIM   128          // EMB+RDIM+SDIM
#define HDIM    512
#define G4      2048         // 4*HDIM
#define ITEMS   10000
#define NPAD    10112        // 79*128 (N padded to tile multiple)
#define TBROWS  12800        // T*B
#define KLIN    544          // HDIM + SDIM

typedef unsigned short u16;
typedef __attribute__((ext_vector_type(8))) short  bf16x8;  // 8 bf16 (4 VGPRs)
typedef __attribute__((ext_vector_type(4))) float  f32x4;

__device__ __forceinline__ u16 f2bf(float x) {
  unsigned u = __float_as_uint(x);
  u = u + 0x7fffu + ((u >> 16) & 1u);   // RNE
  return (u16)(u >> 16);
}
__device__ __forceinline__ float bf2f(u16 b) { return __uint_as_float(((unsigned)b) << 16); }

// ---------------- workspace layout (bytes) ----------------
#define OFF_SYNC   0UL          // 64 uints barrier counters @0, 2 float sumsq @256
#define OFF_XPROJ  512UL        // bf16 [12800][2048]                = 52,428,800
#define OFF_LININ  52429312UL   // bf16 [12800][544] (h | stat)      = 13,926,400
#define OFF_WLIN   66355712UL   // bf16 [10112][544]                 = 11,001,856
#define OFF_WHH    77357568UL   // bf16 [2048][512]  gate-interleaved=  2,097,152
#define OFF_WIH    79454720UL   // bf16 [2048][128]  gate-interleaved=    524,288
#define OFF_ARS    79979008UL   // bf16 [12800][128]                 =  3,276,800
#define OFF_BIAS   83255808UL   // f32  [2048] (b_ih+b_hh, permuted) =      8,192
#define OFF_HBUF   83264000UL   // bf16 2 x [4 grp][64 cb][32 b][8 j]=    262,144

#define HBUFE 65536             // elems per h buffer (4*64*32*8)
#define GSLAB 16384             // elems per group slice (64*32*8)
#define WPG   8                 // workgroups per batch-group

// ---------------- prep: casts, permutes, gather, l2 partials ----------------
__global__ void prep_kernel(const int* __restrict__ pa, const float* __restrict__ pr,
                            const float* __restrict__ ps, const float* __restrict__ hx,
                            const float* __restrict__ emb,
                            const float* __restrict__ W_ih, const float* __restrict__ W_hh,
                            const float* __restrict__ b_ih, const float* __restrict__ b_hh,
                            const float* __restrict__ W_lin, const float* __restrict__ b_lin,
                            u16* __restrict__ ars, u16* __restrict__ lin_in,
                            u16* __restrict__ wlin, u16* __restrict__ whh, u16* __restrict__ wih,
                            float* __restrict__ bias2, u16* __restrict__ hbuf,
                            float* __restrict__ acc) {
  const int tid0 = blockIdx.x * blockDim.x + threadIdx.x;
  const int np = gridDim.x * blockDim.x;
  float sw = 0.f, sb = 0.f;
  // W_lin cast (+zero pad rows) + Frobenius partial
  for (int i = tid0; i < NPAD * KLIN; i += np) {
    int v = i / KLIN;
    float x = (v < ITEMS) ? W_lin[i] : 0.f;
    wlin[i] = f2bf(x);
    sw += x * x;
  }
  for (int i = tid0; i < ITEMS; i += np) { float x = b_lin[i]; sb += x * x; }
  // W_hh gate-interleaved rows: g' = 4*j + gate  <->  g = gate*512 + j
  for (int i = tid0; i < G4 * HDIM; i += np) {
    int gp = i >> 9, k = i & 511;
    int g = (gp & 3) * 512 + (gp >> 2);
    whh[i] = f2bf(W_hh[g * HDIM + k]);
  }
  for (int i = tid0; i < G4 * INDIM; i += np) {
    int gp = i >> 7, k = i & 127;
    int g = (gp & 3) * 512 + (gp >> 2);
    wih[i] = f2bf(W_ih[g * INDIM + k]);
  }
  for (int i = tid0; i < G4; i += np) {
    int g = (i & 3) * 512 + (i >> 2);
    bias2[i] = b_ih[g] + b_hh[g];
  }
  // ars = [emb | one_hot | stat], bf16
  for (int i = tid0; i < TBROWS * INDIM; i += np) {
    int tb = i >> 7, k = i & 127;
    float v;
    if (k < EMB) {
      v = emb[pa[tb] * EMB + k];
    } else if (k < EMB + RDIM) {
      int idx = (int)floorf((float)RDIM * (2.0f - pr[tb]) * 0.25f);  // == floor(RDIM*(2-r)/4)
      v = ((k - EMB) == idx) ? 1.0f : 0.0f;
    } else {
      v = ps[tb * SDIM + (k - EMB - RDIM)];
    }
    ars[i] = f2bf(v);
  }
  // lin_in statistic tail
  for (int i = tid0; i < TBROWS * SDIM; i += np) {
    int tb = i >> 5, s = i & 31;
    lin_in[(size_t)tb * KLIN + HDIM + s] = f2bf(ps[i]);
  }
  // h0 into blocked double-buffer slot 0: [grp][cb=j>>3][b&31][j&7]
  for (int i = tid0; i < BATCH * HDIM; i += np) {
    int b = i >> 9, k = i & 511;
    hbuf[(((size_t)(b >> 5) * 64 + (k >> 3)) * 32 + (b & 31)) * 8 + (k & 7)] = f2bf(hx[i]);
  }
  // reduce l2 partials: wave shuffle -> LDS -> 1 atomic/block
  __shared__ float red[2][8];
  for (int off = 32; off > 0; off >>= 1) { sw += __shfl_down(sw, off); sb += __shfl_down(sb, off); }
  int lane = threadIdx.x & 63, wv = threadIdx.x >> 6;
  if (lane == 0) { red[0][wv] = sw; red[1][wv] = sb; }
  __syncthreads();
  if (threadIdx.x == 0) {
    float a = 0.f, b = 0.f;
    for (int w = 0; w < (int)(blockDim.x >> 6); ++w) { a += red[0][w]; b += red[1][w]; }
    atomicAdd(&acc[0], a);
    atomicAdd(&acc[1], b);
  }
}

__global__ void l2_kernel(const float* __restrict__ acc, float* __restrict__ out) {
  out[0] = sqrtf(acc[0]) + sqrtf(acc[1]);
}

// ---------------- 128x128-tile bf16 MFMA GEMM, C = A * B^T (+bias) ----------------
// A [M x K] row-major bf16, B [N x K] row-major bf16, BK=32, 4 waves each 64x64.
// EPI=0: store bf16 to Cout[M][N] (xproj). EPI=1: store f32 with n<N bound (pn_outputs).
template <int EPI>
__global__ __launch_bounds__(256) void gemm_bt(const u16* __restrict__ A, const u16* __restrict__ Bm,
                                               const float* __restrict__ bias, void* __restrict__ Cout,
                                               int K, int N) {
  __shared__ u16 Asm[128 * 32];
  __shared__ u16 Bsm[128 * 32];
  const int tid = threadIdx.x;
  const int lane = tid & 63;
  const int wv = tid >> 6;
  const int wm = wv >> 1, wn = wv & 1;
  const int l15 = lane & 15, quad = lane >> 4;
  const int mt = blockIdx.y, nt = blockIdx.x;
  const u16* Ag = A + (size_t)mt * 128 * K;
  const u16* Bg = Bm + (size_t)nt * 128 * K;
  f32x4 acc[4][4] = {};

  for (int k0 = 0; k0 < K; k0 += 32) {
    __syncthreads();                     // previous iter's LDS reads done
    {
      int e = tid * 8;                   // elem offset in 128x32 tile (16B per thread)
      int row = e >> 5, col = e & 31;
      *(bf16x8*)&Asm[e]        = *(const bf16x8*)&Ag[(size_t)row * K + k0 + col];
      *(bf16x8*)&Asm[e + 2048] = *(const bf16x8*)&Ag[(size_t)(row + 64) * K + k0 + col];
      *(bf16x8*)&Bsm[e]        = *(const bf16x8*)&Bg[(size_t)row * K + k0 + col];
      *(bf16x8*)&Bsm[e + 2048] = *(const bf16x8*)&Bg[(size_t)(row + 64) * K + k0 + col];
    }
    __syncthreads();                     // staging visible
    bf16x8 af[4], bfr[4];
#pragma unroll
    for (int mi = 0; mi < 4; ++mi)
      af[mi] = *(const bf16x8*)&Asm[(wm * 64 + mi * 16 + l15) * 32 + quad * 8];
#pragma unroll
    for (int ni = 0; ni < 4; ++ni)
      bfr[ni] = *(const bf16x8*)&Bsm[(wn * 64 + ni * 16 + l15) * 32 + quad * 8];
#pragma unroll
    for (int mi = 0; mi < 4; ++mi)
#pragma unroll
      for (int ni = 0; ni < 4; ++ni)
        acc[mi][ni] = __builtin_amdgcn_mfma_f32_16x16x32_bf16(af[mi], bfr[ni], acc[mi][ni], 0, 0, 0);
  }
  // epilogue: C/D layout col=lane&15, row=quad*4+reg
#pragma unroll
  for (int mi = 0; mi < 4; ++mi) {
#pragma unroll
    for (int ni = 0; ni < 4; ++ni) {
      int ng = nt * 128 + wn * 64 + ni * 16 + l15;
      float bv = (EPI == 0 || ng < N) ? bias[ng] : 0.0f;
#pragma unroll
      for (int r = 0; r < 4; ++r) {
        int mg = mt * 128 + wm * 64 + mi * 16 + quad * 4 + r;
        float v = acc[mi][ni][r] + bv;
        if (EPI == 0) {
          ((u16*)Cout)[(size_t)mg * N + ng] = f2bf(v);
        } else {
          if (ng < N) ((float*)Cout)[(size_t)mg * (size_t)N + ng] = v;
        }
      }
    }
  }
}

// ---------------- LSTM scan: 32 WGs = 4 groups x 8 WGs x 8 waves ----------------
// Group grp owns batch rows [grp*32, grp*32+32). Wave (wg8, wv) owns 32 gate-interleaved
// cols cb = wg8*8+wv (i.e. j in [cb*8, cb*8+8)), with its W_hh slice PRELOADED INTO VGPRS
// (32 x bf16x8 = 128 VGPRs). Gates computed TRANSPOSED (W as MFMA A-operand, h as B) so
// each lane holds all 4 gates (reg 0..3 = i,f,g,o) of a (batch,j) pair -> elementwise is
// fully in-register, no gates-LDS round trip.
__global__ __launch_bounds__(512, 2) void lstm_kernel(const u16* __restrict__ xproj,
                                                      const u16* __restrict__ whh,
                                                      const float* __restrict__ cx,
                                                      u16* __restrict__ hbuf,
                                                      u16* __restrict__ lin_in,
                                                      unsigned* __restrict__ cnt) {
  __shared__ u16 hls[GSLAB];                 // 32KB blocked h slice [64 cb][32 b][8 j]
  const int tid = threadIdx.x;
  const int lane = tid & 63, wv = tid >> 6;  // 8 waves
  const int grp = blockIdx.x >> 3;           // 0..3
  const int wg8 = blockIdx.x & 7;            // 0..7
  const int cb = wg8 * 8 + wv;               // 0..63: col block (32 g' = 8 j)
  const int l15 = lane & 15, quad = lane >> 4;
  const int b0 = grp * 32;
  unsigned* mycnt = cnt + grp * 16;          // 64B-spaced per-group counters

  // ---- preload W_hh fragments into registers: wa[sm][kk], 128 VGPRs ----
  bf16x8 wa[2][16];
  {
    const u16* wp = whh + (size_t)(cb * 32) * HDIM;
#pragma unroll
    for (int sm = 0; sm < 2; ++sm)
#pragma unroll
      for (int kk = 0; kk < 16; ++kk)
        wa[sm][kk] = *(const bf16x8*)&wp[(size_t)(sm * 16 + l15) * HDIM + kk * 32 + quad * 8];
  }
  // ---- cell state: lane owns (b = b0+sn*16+l15, j = cb*8+sm*4+quad) ----
  float c[2][2];
#pragma unroll
  for (int sm = 0; sm < 2; ++sm)
#pragma unroll
    for (int sn = 0; sn < 2; ++sn)
      c[sm][sn] = cx[(size_t)(b0 + sn * 16 + l15) * HDIM + cb * 8 + sm * 4 + quad];

  // ---- prefetch xproj for t=0 (4 gates per (sm,sn) = one uint2) ----
  const u16* xpb = xproj + (size_t)b0 * G4 + cb * 32;
  uint2 xpv[2][2];
#pragma unroll
  for (int sm = 0; sm < 2; ++sm)
#pragma unroll
    for (int sn = 0; sn < 2; ++sn)
      xpv[sm][sn] = *(const uint2*)&xpb[(size_t)(sn * 16 + l15) * G4 + sm * 16 + quad * 4];

  for (int t = 0; t < T_STEPS; ++t) {
    // ---- stage group's h slice (32KB) into LDS, coalesced ----
    const u16* hsrc = hbuf + (size_t)(t & 1) * HBUFE + (size_t)grp * GSLAB;
#pragma unroll
    for (int s = tid; s < GSLAB / 8; s += 512)
      *(bf16x8*)&hls[s * 8] = *(const bf16x8*)&hsrc[s * 8];
    __syncthreads();

    // ---- gates^T (32 g' x 32 b) = Wslice * h^T via 2x2 16x16x32 MFMA, W from regs ----
    f32x4 acc[2][2] = {};
#pragma unroll
    for (int kk = 0; kk < 16; ++kk) {
      // B-frag: h[b = sn*16+l15][k = kk*32+quad*8 ..+8] -> block cb'=kk*4+quad, contiguous
      bf16x8 h0v = *(const bf16x8*)&hls[(((kk * 4 + quad) * 32) + l15) * 8];
      bf16x8 h1v = *(const bf16x8*)&hls[(((kk * 4 + quad) * 32) + 16 + l15) * 8];
      acc[0][0] = __builtin_amdgcn_mfma_f32_16x16x32_bf16(wa[0][kk], h0v, acc[0][0], 0, 0, 0);
      acc[0][1] = __builtin_amdgcn_mfma_f32_16x16x32_bf16(wa[0][kk], h1v, acc[0][1], 0, 0, 0);
      acc[1][0] = __builtin_amdgcn_mfma_f32_16x16x32_bf16(wa[1][kk], h0v, acc[1][0], 0, 0, 0);
      acc[1][1] = __builtin_amdgcn_mfma_f32_16x16x32_bf16(wa[1][kk], h1v, acc[1][1], 0, 0, 0);
    }

    // ---- elementwise in-register: output row = sm*16+quad*4+r -> gate r of j=cb*8+sm*4+quad
    const size_t trow = (size_t)t * BATCH + b0;
    u16* hdst = hbuf + (size_t)((t + 1) & 1) * HBUFE + (size_t)grp * GSLAB;
#pragma unroll
    for (int sm = 0; sm < 2; ++sm)
#pragma unroll
      for (int sn = 0; sn < 2; ++sn) {
        uint2 pk = xpv[sm][sn];
        float gi = acc[sm][sn][0] + bf2f((u16)(pk.x & 0xffffu));
        float gf = acc[sm][sn][1] + bf2f((u16)(pk.x >> 16));
        float gg = acc[sm][sn][2] + bf2f((u16)(pk.y & 0xffffu));
        float go = acc[sm][sn][3] + bf2f((u16)(pk.y >> 16));
        gi = 1.f / (1.f + __expf(-gi));
        gf = 1.f / (1.f + __expf(-gf));
        gg = 1.f - 2.f / (__expf(2.f * gg) + 1.f);   // tanh, inf-safe
        go = 1.f / (1.f + __expf(-go));
        float cn = gf * c[sm][sn] + gi * gg;
        c[sm][sn] = cn;
        float hv = go * (1.f - 2.f / (__expf(2.f * cn) + 1.f));
        u16 hb = f2bf(hv);
        int b = sn * 16 + l15;                        // group-local batch row
        int jlow = sm * 4 + quad;                     // j & 7
        hdst[(size_t)((cb * 32 + b) * 8) + jlow] = hb;
        lin_in[(trow + b) * KLIN + cb * 8 + jlow] = hb;
      }

    // ---- prefetch next step's xproj while stores drain / barrier waits ----
    if (t + 1 < T_STEPS) {
#pragma unroll
      for (int sm = 0; sm < 2; ++sm)
#pragma unroll
        for (int sn = 0; sn < 2; ++sn)
          xpv[sm][sn] = *(const uint2*)&xpb[(size_t)((t + 1) * BATCH + sn * 16 + l15) * G4 +
                                            sm * 16 + quad * 4];
    }

    // ---- per-group barrier: release add, RELAXED poll (no per-poll L2 inv), one acquire
    __syncthreads();
    if (tid == 0) {
      __threadfence();                               // release: drain WG stores to coherence pt
      atomicAdd(mycnt, 1u);
      const unsigned target = (unsigned)(WPG * (t + 1));
      while (__hip_atomic_load(mycnt, __ATOMIC_RELAXED, __HIP_MEMORY_SCOPE_AGENT) < target)
        __builtin_amdgcn_s_sleep(1);
      __threadfence();                               // acquire: invalidate L1/L2 once
    }
    __syncthreads();
  }
}

// ---------------- launch ----------------
extern "C" void kernel_launch(void* const* d_in, const int* in_sizes, int n_in,
                              void* d_out, int out_size, void* d_ws, size_t ws_size,
                              hipStream_t stream) {
  const int*   pa   = (const int*)d_in[0];
  const float* pr   = (const float*)d_in[1];
  const float* ps   = (const float*)d_in[2];
  const float* hx   = (const float*)d_in[3];
  const float* cxp  = (const float*)d_in[4];
  const float* emb  = (const float*)d_in[5];
  const float* wih  = (const float*)d_in[6];
  const float* whh  = (const float*)d_in[7];
  const float* bih  = (const float*)d_in[8];
  const float* bhh  = (const float*)d_in[9];
  const float* wlin = (const float*)d_in[10];
  const float* blin = (const float*)d_in[11];

  char* ws = (char*)d_ws;
  unsigned* cnt   = (unsigned*)(ws + OFF_SYNC);
  float*    acc   = (float*)(ws + 256);
  u16* xprojW = (u16*)(ws + OFF_XPROJ);
  u16* lininW = (u16*)(ws + OFF_LININ);
  u16* wlinW  = (u16*)(ws + OFF_WLIN);
  u16* whhW   = (u16*)(ws + OFF_WHH);
  u16* wihW   = (u16*)(ws + OFF_WIH);
  u16* arsW   = (u16*)(ws + OFF_ARS);
  float* biasW = (float*)(ws + OFF_BIAS);
  u16* hbufW  = (u16*)(ws + OFF_HBUF);
  float* outF = (float*)d_out;

  hipMemsetAsync(d_ws, 0, 512, stream);  // barrier counters + l2 accumulators

  prep_kernel<<<dim3(2048), dim3(256), 0, stream>>>(
      pa, pr, ps, hx, emb, wih, whh, bih, bhh, wlin, blin,
      arsW, lininW, wlinW, whhW, wihW, biasW, hbufW, acc);

  l2_kernel<<<dim3(1), dim3(1), 0, stream>>>(acc, outF + (size_t)out_size - 1);

  // x_proj = ars * W_ih'^T + (b_ih+b_hh)   [12800 x 2048] bf16
  gemm_bt<0><<<dim3(16, 100), dim3(256), 0, stream>>>(arsW, wihW, biasW, (void*)xprojW, INDIM, G4);

  lstm_kernel<<<dim3(32), dim3(512), 0, stream>>>(xprojW, whhW, cxp, hbufW, lininW, cnt);

  // pn = lin_in * W_lin^T + b_lin          [12800 x 10000] f32
  gemm_bt<1><<<dim3(79, 100), dim3(256), 0, stream>>>(lininW, wlinW, blin, (void*)outF, KLIN, ITEMS);
}

// Round 2
// 1296.055 us; speedup vs baseline: 1.5141x; 1.2330x over previous
//
#include <hip/hip_runtime.h>
#include <math.h>
#include <stdint.h>

// ---------------- problem constants ----------------
#define T_STEPS 100
#define BATCH   128
#define EMB     64
#define RDIM    32
#define SDIM    32
#define INDIM   128          // EMB+RDIM+SDIM
#define HDIM    512
#define G4      2048         // 4*HDIM
#define ITEMS   10000
#define NPAD    10112        // 79*128 (N padded to tile multiple)
#define TBROWS  12800        // T*B
#define KLIN    544          // HDIM + SDIM

typedef unsigned short u16;
typedef unsigned long long u64;
typedef __attribute__((ext_vector_type(8))) short  bf16x8;  // 8 bf16 (4 VGPRs)
typedef __attribute__((ext_vector_type(4))) float  f32x4;

__device__ __forceinline__ u16 f2bf(float x) {
  unsigned u = __float_as_uint(x);
  u = u + 0x7fffu + ((u >> 16) & 1u);   // RNE
  return (u16)(u >> 16);
}
__device__ __forceinline__ float bf2f(u16 b) { return __uint_as_float(((unsigned)b) << 16); }

// ---------------- workspace layout (bytes) ----------------
#define OFF_SYNC   0UL          // 64 uints barrier counters @0, 2 float sumsq @256
#define OFF_XPROJ  512UL        // bf16 [12800][2048]                = 52,428,800
#define OFF_LININ  52429312UL   // bf16 [12800][544] (h | stat)      = 13,926,400
#define OFF_WLIN   66355712UL   // bf16 [10112][544]                 = 11,001,856
#define OFF_WHH    77357568UL   // bf16 [2048][512]  gate-interleaved=  2,097,152
#define OFF_WIH    79454720UL   // bf16 [2048][128]  gate-interleaved=    524,288
#define OFF_ARS    79979008UL   // bf16 [12800][128]                 =  3,276,800
#define OFF_BIAS   83255808UL   // f32  [2048] (b_ih+b_hh, permuted) =      8,192
#define OFF_HBUF   83264000UL   // bf16 2 x [4 grp][32 b][512 j]     =    262,144

#define HBUFE 65536             // elems per h buffer (4*32*512)
#define GSLAB 16384             // elems per group slice (32*512)
#define WPG   8                 // workgroups per batch-group

// ---------------- prep: casts, permutes, gather, l2 partials ----------------
__global__ void prep_kernel(const int* __restrict__ pa, const float* __restrict__ pr,
                            const float* __restrict__ ps, const float* __restrict__ hx,
                            const float* __restrict__ emb,
                            const float* __restrict__ W_ih, const float* __restrict__ W_hh,
                            const float* __restrict__ b_ih, const float* __restrict__ b_hh,
                            const float* __restrict__ W_lin, const float* __restrict__ b_lin,
                            u16* __restrict__ ars, u16* __restrict__ lin_in,
                            u16* __restrict__ wlin, u16* __restrict__ whh, u16* __restrict__ wih,
                            float* __restrict__ bias2, u16* __restrict__ hbuf,
                            float* __restrict__ acc) {
  const int tid0 = blockIdx.x * blockDim.x + threadIdx.x;
  const int np = gridDim.x * blockDim.x;
  float sw = 0.f, sb = 0.f;
  // W_lin cast (+zero pad rows) + Frobenius partial
  for (int i = tid0; i < NPAD * KLIN; i += np) {
    int v = i / KLIN;
    float x = (v < ITEMS) ? W_lin[i] : 0.f;
    wlin[i] = f2bf(x);
    sw += x * x;
  }
  for (int i = tid0; i < ITEMS; i += np) { float x = b_lin[i]; sb += x * x; }
  // W_hh gate-interleaved rows: g' = 4*j + gate  <->  g = gate*512 + j
  for (int i = tid0; i < G4 * HDIM; i += np) {
    int gp = i >> 9, k = i & 511;
    int g = (gp & 3) * 512 + (gp >> 2);
    whh[i] = f2bf(W_hh[g * HDIM + k]);
  }
  for (int i = tid0; i < G4 * INDIM; i += np) {
    int gp = i >> 7, k = i & 127;
    int g = (gp & 3) * 512 + (gp >> 2);
    wih[i] = f2bf(W_ih[g * INDIM + k]);
  }
  for (int i = tid0; i < G4; i += np) {
    int g = (i & 3) * 512 + (i >> 2);
    bias2[i] = b_ih[g] + b_hh[g];
  }
  // ars = [emb | one_hot | stat], bf16
  for (int i = tid0; i < TBROWS * INDIM; i += np) {
    int tb = i >> 7, k = i & 127;
    float v;
    if (k < EMB) {
      v = emb[pa[tb] * EMB + k];
    } else if (k < EMB + RDIM) {
      int idx = (int)floorf((float)RDIM * (2.0f - pr[tb]) * 0.25f);  // == floor(RDIM*(2-r)/4)
      v = ((k - EMB) == idx) ? 1.0f : 0.0f;
    } else {
      v = ps[tb * SDIM + (k - EMB - RDIM)];
    }
    ars[i] = f2bf(v);
  }
  // lin_in statistic tail
  for (int i = tid0; i < TBROWS * SDIM; i += np) {
    int tb = i >> 5, s = i & 31;
    lin_in[(size_t)tb * KLIN + HDIM + s] = f2bf(ps[i]);
  }
  // h0 into row-major double-buffer slot 0: [grp][b&31][j]
  for (int i = tid0; i < BATCH * HDIM; i += np) {
    int b = i >> 9, k = i & 511;
    hbuf[(size_t)(b >> 5) * GSLAB + (size_t)(b & 31) * HDIM + k] = f2bf(hx[i]);
  }
  // reduce l2 partials: wave shuffle -> LDS -> 1 atomic/block
  __shared__ float red[2][8];
  for (int off = 32; off > 0; off >>= 1) { sw += __shfl_down(sw, off); sb += __shfl_down(sb, off); }
  int lane = threadIdx.x & 63, wv = threadIdx.x >> 6;
  if (lane == 0) { red[0][wv] = sw; red[1][wv] = sb; }
  __syncthreads();
  if (threadIdx.x == 0) {
    float a = 0.f, b = 0.f;
    for (int w = 0; w < (int)(blockDim.x >> 6); ++w) { a += red[0][w]; b += red[1][w]; }
    atomicAdd(&acc[0], a);
    atomicAdd(&acc[1], b);
  }
}

__global__ void l2_kernel(const float* __restrict__ acc, float* __restrict__ out) {
  out[0] = sqrtf(acc[0]) + sqrtf(acc[1]);
}

// ---------------- 128x128-tile bf16 MFMA GEMM, C = A * B^T (+bias) ----------------
template <int EPI>
__global__ __launch_bounds__(256) void gemm_bt(const u16* __restrict__ A, const u16* __restrict__ Bm,
                                               const float* __restrict__ bias, void* __restrict__ Cout,
                                               int K, int N) {
  __shared__ u16 Asm[128 * 32];
  __shared__ u16 Bsm[128 * 32];
  const int tid = threadIdx.x;
  const int lane = tid & 63;
  const int wv = tid >> 6;
  const int wm = wv >> 1, wn = wv & 1;
  const int l15 = lane & 15, quad = lane >> 4;
  const int mt = blockIdx.y, nt = blockIdx.x;
  const u16* Ag = A + (size_t)mt * 128 * K;
  const u16* Bg = Bm + (size_t)nt * 128 * K;
  f32x4 acc[4][4] = {};

  for (int k0 = 0; k0 < K; k0 += 32) {
    __syncthreads();                     // previous iter's LDS reads done
    {
      int e = tid * 8;                   // elem offset in 128x32 tile (16B per thread)
      int row = e >> 5, col = e & 31;
      *(bf16x8*)&Asm[e]        = *(const bf16x8*)&Ag[(size_t)row * K + k0 + col];
      *(bf16x8*)&Asm[e + 2048] = *(const bf16x8*)&Ag[(size_t)(row + 64) * K + k0 + col];
      *(bf16x8*)&Bsm[e]        = *(const bf16x8*)&Bg[(size_t)row * K + k0 + col];
      *(bf16x8*)&Bsm[e + 2048] = *(const bf16x8*)&Bg[(size_t)(row + 64) * K + k0 + col];
    }
    __syncthreads();                     // staging visible
    bf16x8 af[4], bfr[4];
#pragma unroll
    for (int mi = 0; mi < 4; ++mi)
      af[mi] = *(const bf16x8*)&Asm[(wm * 64 + mi * 16 + l15) * 32 + quad * 8];
#pragma unroll
    for (int ni = 0; ni < 4; ++ni)
      bfr[ni] = *(const bf16x8*)&Bsm[(wn * 64 + ni * 16 + l15) * 32 + quad * 8];
#pragma unroll
    for (int mi = 0; mi < 4; ++mi)
#pragma unroll
      for (int ni = 0; ni < 4; ++ni)
        acc[mi][ni] = __builtin_amdgcn_mfma_f32_16x16x32_bf16(af[mi], bfr[ni], acc[mi][ni], 0, 0, 0);
  }
  // epilogue: C/D layout col=lane&15, row=quad*4+reg
#pragma unroll
  for (int mi = 0; mi < 4; ++mi) {
#pragma unroll
    for (int ni = 0; ni < 4; ++ni) {
      int ng = nt * 128 + wn * 64 + ni * 16 + l15;
      float bv = (EPI == 0 || ng < N) ? bias[ng] : 0.0f;
#pragma unroll
      for (int r = 0; r < 4; ++r) {
        int mg = mt * 128 + wm * 64 + mi * 16 + quad * 4 + r;
        float v = acc[mi][ni][r] + bv;
        if (EPI == 0) {
          ((u16*)Cout)[(size_t)mg * N + ng] = f2bf(v);
        } else {
          if (ng < N) ((float*)Cout)[(size_t)mg * (size_t)N + ng] = v;
        }
      }
    }
  }
}

// ---------------- LSTM scan: 32 WGs = 4 groups x 8 WGs x 8 waves ----------------
// Cross-WG h exchange uses coherence-point (sc0/sc1) 8B atomics exclusively: no
// __threadfence (no buffer_wbl2 / buffer_inv on the critical path, L2 stays warm for
// xproj). W_hh slice pinned in VGPRs via asm. h global layout [grp][b 32][j 512];
// LDS copy XOR-swizzled (byte ^= (b&7)<<4) for conflict-free ds_read_b128.
__global__ __launch_bounds__(512, 2) void lstm_kernel(const u16* __restrict__ xproj,
                                                      const u16* __restrict__ whh,
                                                      const float* __restrict__ cx,
                                                      u16* __restrict__ hbuf,
                                                      u16* __restrict__ lin_in,
                                                      unsigned* __restrict__ cnt) {
  __shared__ u16 hls[GSLAB];        // 32KB swizzled [32 b][512 j]
  __shared__ u16 hout[32 * 64];     // 4KB  swizzled [32 b][64 j-slice of this WG]
  const int tid = threadIdx.x;
  const int lane = tid & 63, wv = tid >> 6;  // 8 waves
  const int grp = blockIdx.x & 3;            // adjacent blocks -> same group (2 XCDs/group)
  const int wg8 = blockIdx.x >> 2;           // 0..7
  const int cb = wg8 * 8 + wv;               // 0..63: col block (32 g' = 8 j)
  const int l15 = lane & 15, quad = lane >> 4;
  const int b0 = grp * 32;
  unsigned* mycnt = cnt + grp * 16;          // 64B-spaced per-group counters

  // ---- preload W_hh fragments into registers and PIN them (prevent remat) ----
  bf16x8 wa[2][16];
  {
    const u16* wp = whh + (size_t)(cb * 32) * HDIM;
#pragma unroll
    for (int sm = 0; sm < 2; ++sm)
#pragma unroll
      for (int kk = 0; kk < 16; ++kk) {
        wa[sm][kk] = *(const bf16x8*)&wp[(size_t)(sm * 16 + l15) * HDIM + kk * 32 + quad * 8];
        asm volatile("" : "+v"(wa[sm][kk]));
      }
  }
  // ---- cell state: lane owns (b = b0+sn*16+l15, j = cb*8+sm*4+quad) ----
  float c[2][2];
#pragma unroll
  for (int sm = 0; sm < 2; ++sm)
#pragma unroll
    for (int sn = 0; sn < 2; ++sn)
      c[sm][sn] = cx[(size_t)(b0 + sn * 16 + l15) * HDIM + cb * 8 + sm * 4 + quad];

  // ---- prefetch xproj for t=0 (4 gates per (sm,sn) = one uint2) ----
  const u16* xpb = xproj + (size_t)b0 * G4 + cb * 32;
  uint2 xpv[2][2];
#pragma unroll
  for (int sm = 0; sm < 2; ++sm)
#pragma unroll
    for (int sn = 0; sn < 2; ++sn)
      xpv[sm][sn] = *(const uint2*)&xpb[(size_t)(sn * 16 + l15) * G4 + sm * 16 + quad * 4];

  char* hlsb = (char*)hls;
  char* houtb = (char*)hout;

  for (int t = 0; t < T_STEPS; ++t) {
    // ---- stage group's h (32KB) via coherent 8B loads into swizzled LDS ----
    {
      const u64* hs = (const u64*)(hbuf + (size_t)(t & 1) * HBUFE + (size_t)grp * GSLAB);
      u64 tmp[8];
#pragma unroll
      for (int i = 0; i < 8; ++i)
        tmp[i] = __hip_atomic_load(hs + tid + i * 512, __ATOMIC_RELAXED, __HIP_MEMORY_SCOPE_AGENT);
#pragma unroll
      for (int i = 0; i < 8; ++i) {
        int o = (tid + i * 512) * 8;     // linear byte offset in [32][1024B]
        int b = o >> 10, col = o & 1023;
        *(u64*)&hlsb[b * 1024 + (col ^ ((b & 7) << 4))] = tmp[i];
      }
    }
    __syncthreads();

    // ---- gates^T (32 g' x 32 b) = Wslice * h^T via 2x2 16x16x32 MFMA, W in regs ----
    f32x4 acc[2][2] = {};
#pragma unroll
    for (int kk = 0; kk < 16; ++kk) {
      int csw = (kk * 64 + quad * 16) ^ ((l15 & 7) << 4);
      bf16x8 h0v = *(const bf16x8*)&hlsb[l15 * 1024 + csw];
      bf16x8 h1v = *(const bf16x8*)&hlsb[(16 + l15) * 1024 + csw];
      acc[0][0] = __builtin_amdgcn_mfma_f32_16x16x32_bf16(wa[0][kk], h0v, acc[0][0], 0, 0, 0);
      acc[0][1] = __builtin_amdgcn_mfma_f32_16x16x32_bf16(wa[0][kk], h1v, acc[0][1], 0, 0, 0);
      acc[1][0] = __builtin_amdgcn_mfma_f32_16x16x32_bf16(wa[1][kk], h0v, acc[1][0], 0, 0, 0);
      acc[1][1] = __builtin_amdgcn_mfma_f32_16x16x32_bf16(wa[1][kk], h1v, acc[1][1], 0, 0, 0);
    }

    // ---- elementwise in-register; h -> hout LDS (swizzled [32][64]) ----
#pragma unroll
    for (int sm = 0; sm < 2; ++sm)
#pragma unroll
      for (int sn = 0; sn < 2; ++sn) {
        uint2 pk = xpv[sm][sn];
        float gi = acc[sm][sn][0] + bf2f((u16)(pk.x & 0xffffu));
        float gf = acc[sm][sn][1] + bf2f((u16)(pk.x >> 16));
        float gg = acc[sm][sn][2] + bf2f((u16)(pk.y & 0xffffu));
        float go = acc[sm][sn][3] + bf2f((u16)(pk.y >> 16));
        gi = 1.f / (1.f + __expf(-gi));
        gf = 1.f / (1.f + __expf(-gf));
        gg = 1.f - 2.f / (__expf(2.f * gg) + 1.f);   // tanh, inf-safe
        go = 1.f / (1.f + __expf(-go));
        float cn = gf * c[sm][sn] + gi * gg;
        c[sm][sn] = cn;
        float hv = go * (1.f - 2.f / (__expf(2.f * cn) + 1.f));
        int b = sn * 16 + l15;
        int colb = (wv * 8 + sm * 4 + quad) * 2;     // byte col in 128B row
        *(u16*)&houtb[b * 128 + (colb ^ ((b & 7) << 3))] = f2bf(hv);
      }
    __syncthreads();   // hout visible to all waves

    // ---- copy-out: coherent 8B store to hbuf + regular 8B store to lin_in ----
    {
      int b = tid >> 4, c8 = (tid & 15) * 8;         // byte col
      u64 hv = *(const u64*)&houtb[b * 128 + (c8 ^ ((b & 7) << 3))];
      u16* gdst = hbuf + (size_t)((t + 1) & 1) * HBUFE + (size_t)grp * GSLAB +
                  (size_t)b * HDIM + wg8 * 64 + (tid & 15) * 4;
      __hip_atomic_store((u64*)gdst, hv, __ATOMIC_RELAXED, __HIP_MEMORY_SCOPE_AGENT);
      *(u64*)&lin_in[((size_t)t * BATCH + b0 + b) * KLIN + wg8 * 64 + (tid & 15) * 4] = hv;
    }

    // ---- prefetch next step's xproj (L2 stays warm: no invalidates anymore) ----
    if (t + 1 < T_STEPS) {
#pragma unroll
      for (int sm = 0; sm < 2; ++sm)
#pragma unroll
        for (int sn = 0; sn < 2; ++sn)
          xpv[sm][sn] = *(const uint2*)&xpb[(size_t)((t + 1) * BATCH + sn * 16 + l15) * G4 +
                                            sm * 16 + quad * 4];
    }

    // ---- per-group barrier: syncthreads drains vmcnt (sc1 stores -> visible),
    //      then relaxed fetch_add + relaxed poll. No cache maintenance needed. ----
    __syncthreads();
    if (tid == 0) {
      __hip_atomic_fetch_add(mycnt, 1u, __ATOMIC_RELAXED, __HIP_MEMORY_SCOPE_AGENT);
      const unsigned target = (unsigned)(WPG * (t + 1));
      while (__hip_atomic_load(mycnt, __ATOMIC_RELAXED, __HIP_MEMORY_SCOPE_AGENT) < target)
        __builtin_amdgcn_s_sleep(1);
    }
    __syncthreads();
  }
}

// ---------------- launch ----------------
extern "C" void kernel_launch(void* const* d_in, const int* in_sizes, int n_in,
                              void* d_out, int out_size, void* d_ws, size_t ws_size,
                              hipStream_t stream) {
  const int*   pa   = (const int*)d_in[0];
  const float* pr   = (const float*)d_in[1];
  const float* ps   = (const float*)d_in[2];
  const float* hx   = (const float*)d_in[3];
  const float* cxp  = (const float*)d_in[4];
  const float* emb  = (const float*)d_in[5];
  const float* wih  = (const float*)d_in[6];
  const float* whh  = (const float*)d_in[7];
  const float* bih  = (const float*)d_in[8];
  const float* bhh  = (const float*)d_in[9];
  const float* wlin = (const float*)d_in[10];
  const float* blin = (const float*)d_in[11];

  char* ws = (char*)d_ws;
  unsigned* cnt   = (unsigned*)(ws + OFF_SYNC);
  float*    acc   = (float*)(ws + 256);
  u16* xprojW = (u16*)(ws + OFF_XPROJ);
  u16* lininW = (u16*)(ws + OFF_LININ);
  u16* wlinW  = (u16*)(ws + OFF_WLIN);
  u16* whhW   = (u16*)(ws + OFF_WHH);
  u16* wihW   = (u16*)(ws + OFF_WIH);
  u16* arsW   = (u16*)(ws + OFF_ARS);
  float* biasW = (float*)(ws + OFF_BIAS);
  u16* hbufW  = (u16*)(ws + OFF_HBUF);
  float* outF = (float*)d_out;

  hipMemsetAsync(d_ws, 0, 512, stream);  // barrier counters + l2 accumulators

  prep_kernel<<<dim3(2048), dim3(256), 0, stream>>>(
      pa, pr, ps, hx, emb, wih, whh, bih, bhh, wlin, blin,
      arsW, lininW, wlinW, whhW, wihW, biasW, hbufW, acc);

  l2_kernel<<<dim3(1), dim3(1), 0, stream>>>(acc, outF + (size_t)out_size - 1);

  // x_proj = ars * W_ih'^T + (b_ih+b_hh)   [12800 x 2048] bf16
  gemm_bt<0><<<dim3(16, 100), dim3(256), 0, stream>>>(arsW, wihW, biasW, (void*)xprojW, INDIM, G4);

  lstm_kernel<<<dim3(32), dim3(512), 0, stream>>>(xprojW, whhW, cxp, hbufW, lininW, cnt);

  // pn = lin_in * W_lin^T + b_lin          [12800 x 10000] f32
  gemm_bt<1><<<dim3(79, 100), dim3(256), 0, stream>>>(lininW, wlinW, blin, (void*)outF, KLIN, ITEMS);
}